// Round 7
// baseline (315.871 us; speedup 1.0000x reference)
//
#include <hip/hip_runtime.h>

#define NB 256   // batch
#define NT 512   // time steps
#define ND 128   // input dim
#define NU 128   // hidden dim
#define NC 64    // classes
#define NM (NB * NT)   // 131072 flat rows
#define YP 136         // LDS row pitch in halfs (272B: 16B-aligned, 2-way banks max)

typedef _Float16 half2v __attribute__((ext_vector_type(2)));
typedef _Float16 half4v __attribute__((ext_vector_type(4)));
typedef _Float16 half8v __attribute__((ext_vector_type(8)));
typedef float f32x4 __attribute__((ext_vector_type(4)));
typedef float v2f __attribute__((ext_vector_type(2)));

#define MFMA(a, b, c) __builtin_amdgcn_mfma_f32_16x16x32_f16((a), (b), (c), 0, 0, 0)

// packed f32x2 -> f16x2
__device__ __forceinline__ half2v pk2(float a, float b) {
  return __builtin_bit_cast(half2v, __builtin_amdgcn_cvt_pkrtz(a, b));
}

// tanh from pre-scaled s=2x: tanh(x) = 1 - 2/(e^s+1); exact limits at +-inf.
__device__ __forceinline__ float tanh_s(float s) {
  float e = __expf(s);
  return fmaf(-2.0f, __builtin_amdgcn_rcpf(e + 1.0f), 1.0f);
}

// LDS-only barrier (no vmem drain -> prefetches/stores stay in flight).
__device__ __forceinline__ void wg_barrier() {
  asm volatile("s_waitcnt lgkmcnt(0)\n\ts_barrier" ::: "memory");
}

__device__ __forceinline__ half8v cvt8(const float4& a, const float4& b) {
  half2v p0 = pk2(a.x, a.y), p1 = pk2(a.z, a.w);
  half2v p2 = pk2(b.x, b.y), p3 = pk2(b.z, b.w);
  return (half8v){p0[0], p0[1], p1[0], p1[1], p2[0], p2[1], p3[0], p3[1]};
}

// Workspace layouts (internal, chosen for coalescing):
//   TH[ht][flat_row][16]  halfs  (ht = hidden/16)   -> K1 stores contiguous
//   Y [kk][flat_row][32]  halfs  (kk = hidden/32)   -> K3 reads 16B/lane

// ===================== K1: TH = tanh(x @ W1 + b1) =====================
// 512 blocks x 256 thr x 4 passes; W1 frags hoisted to regs; stores coalesced.
__global__ __launch_bounds__(256, 2) void k1_inproj(
    const float* __restrict__ x, const float* __restrict__ W1,
    const float* __restrict__ b1v, _Float16* __restrict__ TH)
{
  __shared__ _Float16 W1T[ND * YP];  // W1^T[n][k], pre-scaled by 2
  const int tid = (int)threadIdx.x;
  for (int i = tid; i < ND * NU; i += 256) {
    int k = i >> 7, n = i & 127;
    W1T[n * YP + k] = (_Float16)(2.0f * W1[i]);
  }
  __syncthreads();

  const int L = tid & 63, wv = tid >> 6;
  const int v = L & 15, q = L >> 4;

  // hoist W1T A-frags to registers (8 tiles x 4 kk)
  half8v w1f[8][4];
#pragma unroll
  for (int ht = 0; ht < 8; ++ht)
#pragma unroll
    for (int kk = 0; kk < 4; ++kk)
      w1f[ht][kk] = *(const half8v*)&W1T[(16 * ht + v) * YP + 32 * kk + 8 * q];
  f32x4 b1f[8];
#pragma unroll
  for (int ht = 0; ht < 8; ++ht) {
    float4 bb = *(const float4*)&b1v[16 * ht + 4 * q];
    b1f[ht] = (f32x4){2.f * bb.x, 2.f * bb.y, 2.f * bb.z, 2.f * bb.w};
  }

#pragma unroll 1
  for (int pass = 0; pass < 4; ++pass) {
    const int m0 = (int)blockIdx.x * 256 + pass * 64 + wv * 16;
    const float* xr = x + (size_t)(m0 + v) * ND + 8 * q;
    half8v xf[4];
#pragma unroll
    for (int kk = 0; kk < 4; ++kk) {
      float4 a = *(const float4*)(xr + 32 * kk);
      float4 b = *(const float4*)(xr + 32 * kk + 4);
      xf[kk] = cvt8(a, b);
    }
#pragma unroll
    for (int ht = 0; ht < 8; ++ht) {
      f32x4 acc = b1f[ht];
#pragma unroll
      for (int kk = 0; kk < 4; ++kk) acc = MFMA(w1f[ht][kk], xf[kk], acc);
      half2v zlo = pk2(tanh_s(acc[0]), tanh_s(acc[1]));
      half2v zhi = pk2(tanh_s(acc[2]), tanh_s(acc[3]));
      half4v z = {zlo[0], zlo[1], zhi[0], zhi[1]};
      // coalesced: wave covers contiguous 512B per tile
      *(half4v*)&TH[(size_t)ht * NM * 16 + (size_t)(m0 + v) * 16 + 4 * q] = z;
    }
  }
}

// ===================== K2: serial recurrence =====================
// 16 blocks x 4 waves; wave w owns hidden [32w, 32w+32) (col-tiles 2w, 2w+1).
__global__ __launch_bounds__(256, 1) void k2_recur(
    const _Float16* __restrict__ TH, const float* __restrict__ W2,
    const float* __restrict__ b2v, _Float16* __restrict__ Yws)
{
  __shared__ _Float16 Ybuf[2][16 * YP];  // y image [v][h], double-buffered

  const int tid = (int)threadIdx.x;
  const int w = tid >> 6;  // 0..3
  const int L = tid & 63;
  const int v = L & 15, q = L >> 4;
  const int b0 = (int)blockIdx.x * 16;

  // A-frags of W2^T for col-tiles 2w, 2w+1 (scaled 2x)
  half8v w2f[2][4];
#pragma unroll
  for (int c = 0; c < 2; ++c)
#pragma unroll
    for (int kk = 0; kk < 4; ++kk) {
      half8v h;
#pragma unroll
      for (int j = 0; j < 8; ++j)
        h[j] = (_Float16)(2.0f * W2[(size_t)(32 * kk + 8 * q + j) * NU + 16 * (2 * w + c) + v]);
      w2f[c][kk] = h;
    }
  f32x4 b2f0, b2f1;
  {
    float4 a = *(const float4*)&b2v[16 * (2 * w) + 4 * q];
    float4 b = *(const float4*)&b2v[16 * (2 * w + 1) + 4 * q];
    b2f0 = (f32x4){2.f * a.x, 2.f * a.y, 2.f * a.z, 2.f * a.w};
    b2f1 = (f32x4){2.f * b.x, 2.f * b.y, 2.f * b.z, 2.f * b.w};
  }

  // TH[ht][row*NT+t][16]: our tiles ht = 2w, 2w+1
  const _Float16* thp0 = TH + (size_t)(2 * w) * NM * 16 + (size_t)(b0 + v) * NT * 16 + 4 * q;
  const _Float16* thp1 = thp0 + (size_t)NM * 16;
  // Y[kk=w][row*NT+t][32]: offsets 4q (tile 2w) and 16+4q (tile 2w+1)
  _Float16* ypw = Yws + (size_t)w * NM * 32 + (size_t)(b0 + v) * NT * 32 + 4 * q;

  // th prefetch ring, 4 deep, both tiles
  half4v th0[4], th1[4];
#pragma unroll
  for (int i = 0; i < 4; ++i) {
    th0[i] = *(const half4v*)(thp0 + (size_t)i * 16);
    th1[i] = *(const half4v*)(thp1 + (size_t)i * 16);
  }

  f32x4 racc0 = b2f0, racc1 = b2f1;  // r_0 (y_{-1} = 0)
  _Float16* wr = &Ybuf[0][0] + v * YP + 32 * w + 4 * q;
  const _Float16* rd = &Ybuf[0][0] + v * YP + 8 * q;

#define K2STEP(T_, I_)                                                        \
  {                                                                           \
    const int t_ = (T_);                                                      \
    const int bo_ = (t_ & 1) * (16 * YP);                                     \
    half2v zlo0 = pk2(tanh_s(racc0[0]), tanh_s(racc0[1]));                    \
    half2v zhi0 = pk2(tanh_s(racc0[2]), tanh_s(racc0[3]));                    \
    half2v zlo1 = pk2(tanh_s(racc1[0]), tanh_s(racc1[1]));                    \
    half2v zhi1 = pk2(tanh_s(racc1[2]), tanh_s(racc1[3]));                    \
    half4v t40 = th0[I_], t41 = th1[I_];                                      \
    half2v yl0 = zlo0 + (half2v){t40[0], t40[1]};                             \
    half2v yh0 = zhi0 + (half2v){t40[2], t40[3]};                             \
    half2v yl1 = zlo1 + (half2v){t41[0], t41[1]};                             \
    half2v yh1 = zhi1 + (half2v){t41[2], t41[3]};                             \
    half4v y0 = {yl0[0], yl0[1], yh0[0], yh0[1]};                             \
    half4v y1 = {yl1[0], yl1[1], yh1[0], yh1[1]};                             \
    *(half4v*)(wr + bo_) = y0;                                                \
    *(half4v*)(wr + bo_ + 16) = y1;                                           \
    *(half4v*)(ypw + (size_t)t_ * 32) = y0;      /* fire-and-forget */        \
    *(half4v*)(ypw + (size_t)t_ * 32 + 16) = y1;                              \
    {                                                                         \
      int tn = t_ + 4; tn = tn < NT ? tn : NT - 1;                            \
      th0[I_] = *(const half4v*)(thp0 + (size_t)tn * 16);                     \
      th1[I_] = *(const half4v*)(thp1 + (size_t)tn * 16);                     \
    }                                                                         \
    wg_barrier();                                                             \
    half8v yf0 = *(const half8v*)(rd + bo_ + 0);                              \
    half8v yf1 = *(const half8v*)(rd + bo_ + 32);                             \
    half8v yf2 = *(const half8v*)(rd + bo_ + 64);                             \
    half8v yf3 = *(const half8v*)(rd + bo_ + 96);                             \
    racc0 = b2f0;  racc1 = b2f1;                                              \
    racc0 = MFMA(w2f[0][0], yf0, racc0);  racc1 = MFMA(w2f[1][0], yf0, racc1);\
    racc0 = MFMA(w2f[0][1], yf1, racc0);  racc1 = MFMA(w2f[1][1], yf1, racc1);\
    racc0 = MFMA(w2f[0][2], yf2, racc0);  racc1 = MFMA(w2f[1][2], yf2, racc1);\
    racc0 = MFMA(w2f[0][3], yf3, racc0);  racc1 = MFMA(w2f[1][3], yf3, racc1);\
  }

#pragma unroll 1
  for (int t = 0; t < NT; t += 4) {
    K2STEP(t + 0, 0)
    K2STEP(t + 1, 1)
    K2STEP(t + 2, 2)
    K2STEP(t + 3, 3)
  }
}

// ===================== K3: out = Y @ Wc + bc =====================
// 512 blocks x 256 thr x 4 passes; Wc frags in regs.
__global__ __launch_bounds__(256, 2) void k3_head(
    const _Float16* __restrict__ Y, const float* __restrict__ Wc,
    const float* __restrict__ bcv, float* __restrict__ out)
{
  __shared__ _Float16 WcT[NC * YP];  // Wc^T[c][k]
  const int tid = (int)threadIdx.x;
  for (int i = tid; i < NU * NC; i += 256) {
    int k = i >> 6, c = i & 63;
    WcT[c * YP + k] = (_Float16)Wc[i];
  }
  __syncthreads();

  const int L = tid & 63, wv = tid >> 6;
  const int v = L & 15, q = L >> 4;

  half8v wcf[4][4];
#pragma unroll
  for (int ct = 0; ct < 4; ++ct)
#pragma unroll
    for (int kk = 0; kk < 4; ++kk)
      wcf[ct][kk] = *(const half8v*)&WcT[(16 * ct + v) * YP + 32 * kk + 8 * q];
  f32x4 bcf[4];
#pragma unroll
  for (int ct = 0; ct < 4; ++ct) {
    float4 bb = *(const float4*)&bcv[16 * ct + 4 * q];
    bcf[ct] = (f32x4){bb.x, bb.y, bb.z, bb.w};
  }

#pragma unroll 1
  for (int pass = 0; pass < 4; ++pass) {
    const int m0 = (int)blockIdx.x * 256 + pass * 64 + wv * 16;
    half8v yf[4];
#pragma unroll
    for (int kk = 0; kk < 4; ++kk)
      yf[kk] = *(const half8v*)(Y + (size_t)kk * NM * 32 + (size_t)(m0 + v) * 32 + 8 * q);
    float* op = out + (size_t)(m0 + v) * NC + 4 * q;
#pragma unroll
    for (int ct = 0; ct < 4; ++ct) {
      f32x4 acc = bcf[ct];
#pragma unroll
      for (int kk = 0; kk < 4; ++kk) acc = MFMA(wcf[ct][kk], yf[kk], acc);
      *(float4*)(op + 16 * ct) = (float4){acc[0], acc[1], acc[2], acc[3]};
    }
  }
}

// ===================== fallback (round-2 kernel, no workspace) =====================
__device__ __forceinline__ float fast_tanh(float x) {
  float e = __expf(2.0f * x);
  return 1.0f - 2.0f / (e + 1.0f);
}
__device__ __forceinline__ float bcast(float val, int i) {
  return __builtin_bit_cast(float, __builtin_amdgcn_readlane(__builtin_bit_cast(int, val), i));
}

__global__ __launch_bounds__(256, 1) void rnn_fallback(
    const float* __restrict__ x, const float* __restrict__ W1,
    const float* __restrict__ b1v, const float* __restrict__ W2,
    const float* __restrict__ b2v, const float* __restrict__ Wc,
    const float* __restrict__ bcv, float* __restrict__ out)
{
  __shared__ float xring[16][ND];
  __shared__ float pH[2][4][NU];
  __shared__ float pR[2][4][NU];
  __shared__ float pC[2][4][NC];

  const int tid  = (int)threadIdx.x;
  const int lane = tid & 63;
  const int kg   = tid >> 6;
  const int b    = (int)blockIdx.x;
  const float4* xr4 = (const float4*)(x + (size_t)b * NT * ND);

  v2f w1f[32], w2f[32];
  float wcf[32];
#pragma unroll
  for (int i = 0; i < 32; ++i) {
    int k = kg * 32 + i;
    w1f[i] = (v2f){W1[k * NU + lane], W1[k * NU + lane + 64]};
    w2f[i] = (v2f){W2[k * NU + lane], W2[k * NU + lane + 64]};
    wcf[i] = Wc[k * NC + lane];
  }
  const float biasc = bcv[lane];
  float bias1 = 0.f, bias2 = 0.f;
  if (lane < 32) { bias1 = b1v[kg * 32 + lane]; bias2 = b2v[kg * 32 + lane]; }

  float4 stg = make_float4(0.f, 0.f, 0.f, 0.f);
  if (lane < 32) {
    float4 a0 = xr4[(kg + 0) * 32 + lane];
    float4 a1 = xr4[(kg + 4) * 32 + lane];
    ((float4*)xring[kg + 0])[lane] = a0;
    ((float4*)xring[kg + 4])[lane] = a1;
    stg = xr4[(kg + 8) * 32 + lane];
  }
  float yseg = 0.f;
  wg_barrier();

  for (int t = 0; t < NT; ++t) {
    const int pb = t & 1;
    v2f accH0 = {0.f, 0.f}, accH1 = {0.f, 0.f};
    const float4* xb = (const float4*)&xring[t & 15][kg * 32];
#pragma unroll
    for (int i = 0; i < 4; ++i) {
      float4 xa = xb[2 * i];
      float4 xc = xb[2 * i + 1];
      accH0 = w1f[8*i+0] * (v2f){xa.x, xa.x} + accH0;
      accH1 = w1f[8*i+1] * (v2f){xa.y, xa.y} + accH1;
      accH0 = w1f[8*i+2] * (v2f){xa.z, xa.z} + accH0;
      accH1 = w1f[8*i+3] * (v2f){xa.w, xa.w} + accH1;
      accH0 = w1f[8*i+4] * (v2f){xc.x, xc.x} + accH0;
      accH1 = w1f[8*i+5] * (v2f){xc.y, xc.y} + accH1;
      accH0 = w1f[8*i+6] * (v2f){xc.z, xc.z} + accH0;
      accH1 = w1f[8*i+7] * (v2f){xc.w, xc.w} + accH1;
    }
    v2f accH = accH0 + accH1;
    v2f accR0 = {0.f, 0.f}, accR1 = {0.f, 0.f};
    float accC0 = 0.f, accC1 = 0.f;
#pragma unroll
    for (int i = 0; i < 16; ++i) {
      float s0 = bcast(yseg, 2 * i);
      float s1 = bcast(yseg, 2 * i + 1);
      accR0 = w2f[2*i+0] * (v2f){s0, s0} + accR0;
      accR1 = w2f[2*i+1] * (v2f){s1, s1} + accR1;
      accC0 = fmaf(s0, wcf[2*i+0], accC0);
      accC1 = fmaf(s1, wcf[2*i+1], accC1);
    }
    v2f accR = accR0 + accR1;
    float accC = accC0 + accC1;

    pH[pb][kg][lane]      = accH.x;
    pH[pb][kg][lane + 64] = accH.y;
    pR[pb][kg][lane]      = accR.x;
    pR[pb][kg][lane + 64] = accR.y;
    pC[pb][kg][lane]      = accC;

    if (kg == (t & 3)) {
      if (lane < 32) {
        ((float4*)xring[(t + 8) & 15])[lane] = stg;
        int r = t + 12; r = (r < NT) ? r : (NT - 1);
        stg = xr4[r * 32 + lane];
      }
    }
    wg_barrier();
    if (lane < 32) {
      const int j = kg * 32 + lane;
      float hs = bias1, rs = bias2;
#pragma unroll
      for (int g = 0; g < 4; ++g) { hs += pH[pb][g][j]; rs += pR[pb][g][j]; }
      yseg = fast_tanh(hs) + fast_tanh(rs);
    }
    if (kg == ((t + 2) & 3) && t >= 1) {
      float cs = biasc;
#pragma unroll
      for (int g = 0; g < 4; ++g) cs += pC[pb][g][lane];
      out[((size_t)b * NT + (t - 1)) * NC + lane] = cs;
    }
  }
  float accC0 = 0.f, accC1 = 0.f;
#pragma unroll
  for (int i = 0; i < 16; ++i) {
    float s0 = bcast(yseg, 2 * i);
    float s1 = bcast(yseg, 2 * i + 1);
    accC0 = fmaf(s0, wcf[2*i+0], accC0);
    accC1 = fmaf(s1, wcf[2*i+1], accC1);
  }
  pC[0][kg][lane] = accC0 + accC1;
  wg_barrier();
  if (kg == 0) {
    float cs = biasc;
#pragma unroll
    for (int g = 0; g < 4; ++g) cs += pC[0][g][lane];
    out[((size_t)b * NT + (NT - 1)) * NC + lane] = cs;
  }
}

extern "C" void kernel_launch(void* const* d_in, const int* in_sizes, int n_in,
                              void* d_out, int out_size, void* d_ws, size_t ws_size,
                              hipStream_t stream) {
  (void)in_sizes; (void)n_in; (void)out_size;
  const float* x   = (const float*)d_in[0];
  const float* W1  = (const float*)d_in[1];
  const float* b1v = (const float*)d_in[2];
  const float* W2  = (const float*)d_in[3];
  const float* b2v = (const float*)d_in[4];
  const float* Wc  = (const float*)d_in[5];
  const float* bcv = (const float*)d_in[6];
  float* out = (float*)d_out;

  const size_t need = (size_t)NM * NU * 2 * 2;  // TH + Y, f16 each = 64 MiB
  if (ws_size >= need) {
    _Float16* TH = (_Float16*)d_ws;
    _Float16* Yw = TH + (size_t)NM * NU;
    hipLaunchKernelGGL(k1_inproj, dim3(NM / 256), dim3(256), 0, stream, x, W1, b1v, TH);
    hipLaunchKernelGGL(k2_recur, dim3(NB / 16), dim3(256), 0, stream, TH, W2, b2v, Yw);
    hipLaunchKernelGGL(k3_head, dim3(NM / 256), dim3(256), 0, stream, Yw, Wc, bcv, out);
  } else {
    hipLaunchKernelGGL(rnn_fallback, dim3(NB), dim3(256), 0, stream,
                       x, W1, b1v, W2, b2v, Wc, bcv, out);
  }
}